// Round 6
// baseline (124.410 us; speedup 1.0000x reference)
//
#include <hip/hip_runtime.h>
#include <math.h>

#define N_PER_B   262144
#define BATCH     8
#define NFEAT     14
#define TPB       256
#define BPB       256                     // blocks per batch
#define BLOCKS    (BPB * BATCH)           // 2048 total
#define TPBATCH   (BPB * TPB)             // 65536 threads per batch
#define RPT       (N_PER_B / TPBATCH)     // 4 records per thread

// dword-aligned (not 16B-aligned) float4: quat lives at byte offset 56r+28.
typedef float f4u __attribute__((ext_vector_type(4), aligned(4)));

// ---- agent-scope coherent f64 store/load (cross-XCD safe; validated r3) ----
__device__ inline void st_agent(double* p, double v) {
    __hip_atomic_store((unsigned long long*)p,
                       (unsigned long long)__double_as_longlong(v),
                       __ATOMIC_RELAXED, __HIP_MEMORY_SCOPE_AGENT);
}
__device__ inline double ld_agent(const double* p) {
    unsigned long long u = __hip_atomic_load((const unsigned long long*)p,
                       __ATOMIC_RELAXED, __HIP_MEMORY_SCOPE_AGENT);
    return __longlong_as_double((long long)u);
}

// ---- per-quaternion math (fp32, identical to validated rounds 1-5) ----
__device__ inline void quat_accum(float w, float x, float y, float z, double* s) {
    w = fminf(fmaxf(w, -1000.0f), 1000.0f);
    x = fminf(fmaxf(x, -1000.0f), 1000.0f);
    y = fminf(fmaxf(y, -1000.0f), 1000.0f);
    z = fminf(fmaxf(z, -1000.0f), 1000.0f);
    float nrm = sqrtf(w * w + x * x + y * y + z * z);
    nrm = fmaxf(nrm, 1e-8f);
    float inv = 1.0f / nrm;
    w *= inv; x *= inv; y *= inv; z *= inv;
    float r0 = 2.0f * (x * z + w * y);
    float r1 = 2.0f * (y * z - w * x);
    float r2 = 1.0f - 2.0f * (x * x + y * y);
    s[0] += (double)r0 * (double)r0;
    s[1] += (double)r1 * (double)r1;
    s[2] += (double)r2 * (double)r2;
    s[3] += (double)r0 * (double)r1;
    s[4] += (double)r0 * (double)r2;
    s[5] += (double)r1 * (double)r2;
}

// ---- closed-form 3x3 symmetric eigenvalues -> per-batch loss (fp64) ----
__device__ inline double batch_loss(const double* sraw) {
    const double invN = 1.0 / (double)N_PER_B;
    double a00 = sraw[0] * invN, a11 = sraw[1] * invN, a22 = sraw[2] * invN;
    double a01 = sraw[3] * invN, a02 = sraw[4] * invN, a12 = sraw[5] * invN;

    a00 = fmin(fmax(a00, -1e6), 1e6);
    a11 = fmin(fmax(a11, -1e6), 1e6);
    a22 = fmin(fmax(a22, -1e6), 1e6);
    a01 = fmin(fmax(a01, -1e6), 1e6);
    a02 = fmin(fmax(a02, -1e6), 1e6);
    a12 = fmin(fmax(a12, -1e6), 1e6);

    double q  = (a00 + a11 + a22) / 3.0;
    double p1 = a01 * a01 + a02 * a02 + a12 * a12;
    double d0 = a00 - q, d1 = a11 - q, d2 = a22 - q;
    double p2 = d0 * d0 + d1 * d1 + d2 * d2 + 2.0 * p1;

    double eigmax, eigmin;
    if (p2 <= 0.0) {
        eigmax = q;
        eigmin = q;
    } else {
        double p = sqrt(p2 / 6.0);
        double invp = 1.0 / p;
        double b00 = d0 * invp, b11 = d1 * invp, b22 = d2 * invp;
        double b01 = a01 * invp, b02 = a02 * invp, b12 = a12 * invp;
        double detB = b00 * (b11 * b22 - b12 * b12)
                    - b01 * (b01 * b22 - b12 * b02)
                    + b02 * (b01 * b12 - b11 * b02);
        double r = 0.5 * detB;
        r = fmin(1.0, fmax(-1.0, r));
        double phi = acos(r) / 3.0;
        eigmax = q + 2.0 * p * cos(phi);
        eigmin = q + 2.0 * p * cos(phi + 2.0 * M_PI / 3.0);
    }

    double max_safe = fmax(eigmax, 1e-6);
    double min_safe = fmax(eigmin, 1e-6);
    double ratio = max_safe / min_safe;
    ratio = fmin(fmax(ratio, 1.0), 1e6);
    return -log(ratio);
}

// ---- fused kernel: accumulate; last-arriving block finalizes ----
__global__ __launch_bounds__(TPB) void fused_kernel(const float* __restrict__ g,
                                                    float* __restrict__ out,
                                                    double* __restrict__ partials,
                                                    unsigned int* __restrict__ ticket) {
    const int b     = blockIdx.y;
    const int tid_b = blockIdx.x * TPB + threadIdx.x;
    const float* __restrict__ gb = g + (size_t)b * N_PER_B * NFEAT;

    double s[6] = {0, 0, 0, 0, 0, 0};

    #pragma unroll
    for (int k = 0; k < RPT; ++k) {
        const size_t rec = (size_t)(tid_b + k * TPBATCH);
        f4u q = *(const f4u*)(gb + rec * NFEAT + 7);
        quat_accum(q[0], q[1], q[2], q[3], s);
    }

    // 64-lane wave reduction
    #pragma unroll
    for (int off = 32; off > 0; off >>= 1) {
        #pragma unroll
        for (int k = 0; k < 6; ++k) s[k] += __shfl_down(s[k], off);
    }

    __shared__ double lds[TPB / 64][6];
    const int wave = threadIdx.x >> 6;
    const int lane = threadIdx.x & 63;
    if (lane == 0) {
        #pragma unroll
        for (int k = 0; k < 6; ++k) lds[wave][k] = s[k];
    }
    __syncthreads();

    __shared__ unsigned int is_last;
    if (threadIdx.x == 0) {
        double* p = partials + (size_t)(b * BPB + blockIdx.x) * 6;
        #pragma unroll
        for (int k = 0; k < 6; ++k)
            st_agent(&p[k], lds[0][k] + lds[1][k] + lds[2][k] + lds[3][k]);
        __threadfence();
        unsigned int old = __hip_atomic_fetch_add(ticket, 1u,
                               __ATOMIC_ACQ_REL, __HIP_MEMORY_SCOPE_AGENT);
        is_last = (old == (unsigned int)(BLOCKS - 1)) ? 1u : 0u;
    }
    __syncthreads();

    if (!is_last) return;

    // ---- finalize (whole block): reduce 2048x6 partials + eigen + mean ----
    // 32 lanes per batch (8 x 32 = 256 threads); each lane sums 8 partials
    const int bb = threadIdx.x >> 5;
    const int l  = threadIdx.x & 31;
    double t[6] = {0, 0, 0, 0, 0, 0};
    #pragma unroll
    for (int j = 0; j < BPB / 32; ++j) {
        const double* pp = partials + (size_t)(bb * BPB + l + 32 * j) * 6;
        #pragma unroll
        for (int k = 0; k < 6; ++k) t[k] += ld_agent(pp + k);
    }
    #pragma unroll
    for (int off = 16; off > 0; off >>= 1) {
        #pragma unroll
        for (int k = 0; k < 6; ++k) t[k] += __shfl_down(t[k], off, 32);
    }

    __shared__ double Tsum[BATCH][6];
    if (l == 0) {
        #pragma unroll
        for (int k = 0; k < 6; ++k) Tsum[bb][k] = t[k];
    }
    __syncthreads();

    __shared__ double losses[BATCH];
    if (threadIdx.x < BATCH) losses[threadIdx.x] = batch_loss(Tsum[threadIdx.x]);
    __syncthreads();

    if (threadIdx.x == 0) {
        double ssum = 0.0;
        #pragma unroll
        for (int i = 0; i < BATCH; ++i) ssum += losses[i];
        out[0] = (float)(ssum / (double)BATCH);
    }
}

extern "C" void kernel_launch(void* const* d_in, const int* in_sizes, int n_in,
                              void* d_out, int out_size, void* d_ws, size_t ws_size,
                              hipStream_t stream) {
    const float* g = (const float*)d_in[0];
    float* out = (float*)d_out;
    unsigned int* ticket = (unsigned int*)d_ws;            // 4 B, zeroed per call
    double* partials = (double*)((char*)d_ws + 256);       // 2048*6 doubles = 96 KB,
                                                           // fully overwritten per call

    hipMemsetAsync(ticket, 0, sizeof(unsigned int), stream);
    fused_kernel<<<dim3(BPB, BATCH), TPB, 0, stream>>>(g, out, partials, ticket);
}

// Round 7
// 26.316 us; speedup vs baseline: 4.7275x; 4.7275x over previous
//
#include <hip/hip_runtime.h>
#include <math.h>

#define N_PER_B   262144
#define BATCH     8
#define NFEAT     14
#define TPB       256
#define BPB       256                     // blocks per batch
#define BLOCKS    (BPB * BATCH)           // 2048 total
#define TPBATCH   (BPB * TPB)             // 65536 threads per batch
#define RPT       (N_PER_B / TPBATCH)     // 4 records per thread

// dword-aligned (not 16B-aligned) float4: quat lives at byte offset 56r+28,
// which is 4-aligned. gfx950 supports dword-aligned global_load_dwordx4.
typedef float f4u __attribute__((ext_vector_type(4), aligned(4)));

// ---- per-quaternion math (fp32, identical to validated rounds 1-5) ----
__device__ inline void quat_accum(float w, float x, float y, float z, double* s) {
    w = fminf(fmaxf(w, -1000.0f), 1000.0f);
    x = fminf(fmaxf(x, -1000.0f), 1000.0f);
    y = fminf(fmaxf(y, -1000.0f), 1000.0f);
    z = fminf(fmaxf(z, -1000.0f), 1000.0f);
    float nrm = sqrtf(w * w + x * x + y * y + z * z);
    nrm = fmaxf(nrm, 1e-8f);
    float inv = 1.0f / nrm;
    w *= inv; x *= inv; y *= inv; z *= inv;
    float r0 = 2.0f * (x * z + w * y);
    float r1 = 2.0f * (y * z - w * x);
    float r2 = 1.0f - 2.0f * (x * x + y * y);
    s[0] += (double)r0 * (double)r0;
    s[1] += (double)r1 * (double)r1;
    s[2] += (double)r2 * (double)r2;
    s[3] += (double)r0 * (double)r1;
    s[4] += (double)r0 * (double)r2;
    s[5] += (double)r1 * (double)r2;
}

// ---- kernel A: streaming accumulate -> partials[block][6] ----
__global__ __launch_bounds__(TPB) void accum_kernel(const float* __restrict__ g,
                                                    double* __restrict__ partials) {
    const int b     = blockIdx.y;
    const int tid_b = blockIdx.x * TPB + threadIdx.x;
    const float* __restrict__ gb = g + (size_t)b * N_PER_B * NFEAT;

    double s[6] = {0, 0, 0, 0, 0, 0};

    // One unaligned 16B NONTEMPORAL load per record (zero-reuse stream:
    // bypass L2 allocation via the nt flag).
    #pragma unroll
    for (int k = 0; k < RPT; ++k) {
        const size_t rec = (size_t)(tid_b + k * TPBATCH);
        f4u q = __builtin_nontemporal_load((const f4u*)(gb + rec * NFEAT + 7));
        quat_accum(q[0], q[1], q[2], q[3], s);
    }

    // 64-lane wave reduction
    #pragma unroll
    for (int off = 32; off > 0; off >>= 1) {
        #pragma unroll
        for (int k = 0; k < 6; ++k) s[k] += __shfl_down(s[k], off);
    }

    __shared__ double lds[TPB / 64][6];
    const int wave = threadIdx.x >> 6;
    const int lane = threadIdx.x & 63;
    if (lane == 0) {
        #pragma unroll
        for (int k = 0; k < 6; ++k) lds[wave][k] = s[k];
    }
    __syncthreads();
    if (threadIdx.x == 0) {
        double* p = partials + (size_t)(b * BPB + blockIdx.x) * 6;
        #pragma unroll
        for (int k = 0; k < 6; ++k)
            p[k] = lds[0][k] + lds[1][k] + lds[2][k] + lds[3][k];
    }
}

// ---- closed-form 3x3 symmetric eigenvalues -> per-batch loss (fp64) ----
__device__ inline double batch_loss(const double* sraw) {
    const double invN = 1.0 / (double)N_PER_B;
    double a00 = sraw[0] * invN, a11 = sraw[1] * invN, a22 = sraw[2] * invN;
    double a01 = sraw[3] * invN, a02 = sraw[4] * invN, a12 = sraw[5] * invN;

    a00 = fmin(fmax(a00, -1e6), 1e6);
    a11 = fmin(fmax(a11, -1e6), 1e6);
    a22 = fmin(fmax(a22, -1e6), 1e6);
    a01 = fmin(fmax(a01, -1e6), 1e6);
    a02 = fmin(fmax(a02, -1e6), 1e6);
    a12 = fmin(fmax(a12, -1e6), 1e6);

    double q  = (a00 + a11 + a22) / 3.0;
    double p1 = a01 * a01 + a02 * a02 + a12 * a12;
    double d0 = a00 - q, d1 = a11 - q, d2 = a22 - q;
    double p2 = d0 * d0 + d1 * d1 + d2 * d2 + 2.0 * p1;

    double eigmax, eigmin;
    if (p2 <= 0.0) {
        eigmax = q;
        eigmin = q;
    } else {
        double p = sqrt(p2 / 6.0);
        double invp = 1.0 / p;
        double b00 = d0 * invp, b11 = d1 * invp, b22 = d2 * invp;
        double b01 = a01 * invp, b02 = a02 * invp, b12 = a12 * invp;
        double detB = b00 * (b11 * b22 - b12 * b12)
                    - b01 * (b01 * b22 - b12 * b02)
                    + b02 * (b01 * b12 - b11 * b02);
        double r = 0.5 * detB;
        r = fmin(1.0, fmax(-1.0, r));
        double phi = acos(r) / 3.0;
        eigmax = q + 2.0 * p * cos(phi);
        eigmin = q + 2.0 * p * cos(phi + 2.0 * M_PI / 3.0);
    }

    double max_safe = fmax(eigmax, 1e-6);
    double min_safe = fmax(eigmin, 1e-6);
    double ratio = max_safe / min_safe;
    ratio = fmin(fmax(ratio, 1.0), 1e6);
    return -log(ratio);
}

// ---- kernel B: reduce 2048x6 partials + eigen + mean (one block) ----
__global__ void finalize_kernel(const double* __restrict__ partials,
                                float* __restrict__ out) {
    // 32 lanes per batch (8 batches x 32 = 256 threads); each lane sums 8
    const int bb = threadIdx.x >> 5;
    const int l  = threadIdx.x & 31;
    double t[6] = {0, 0, 0, 0, 0, 0};
    #pragma unroll
    for (int j = 0; j < BPB / 32; ++j) {
        const double* pp = partials + (size_t)(bb * BPB + l + 32 * j) * 6;
        #pragma unroll
        for (int k = 0; k < 6; ++k) t[k] += pp[k];
    }
    #pragma unroll
    for (int off = 16; off > 0; off >>= 1) {
        #pragma unroll
        for (int k = 0; k < 6; ++k) t[k] += __shfl_down(t[k], off, 32);
    }

    __shared__ double Tsum[BATCH][6];
    if (l == 0) {
        #pragma unroll
        for (int k = 0; k < 6; ++k) Tsum[bb][k] = t[k];
    }
    __syncthreads();

    __shared__ double losses[BATCH];
    if (threadIdx.x < BATCH) losses[threadIdx.x] = batch_loss(Tsum[threadIdx.x]);
    __syncthreads();

    if (threadIdx.x == 0) {
        double ssum = 0.0;
        #pragma unroll
        for (int i = 0; i < BATCH; ++i) ssum += losses[i];
        out[0] = (float)(ssum / (double)BATCH);
    }
}

extern "C" void kernel_launch(void* const* d_in, const int* in_sizes, int n_in,
                              void* d_out, int out_size, void* d_ws, size_t ws_size,
                              hipStream_t stream) {
    const float* g = (const float*)d_in[0];
    float* out = (float*)d_out;
    double* partials = (double*)d_ws;  // BLOCKS*6 doubles = 96 KB, fully
                                       // overwritten every call (poison-safe)

    accum_kernel<<<dim3(BPB, BATCH), TPB, 0, stream>>>(g, partials);
    finalize_kernel<<<1, TPB, 0, stream>>>(partials, out);
}

// Round 8
// 25.279 us; speedup vs baseline: 4.9215x; 1.0410x over previous
//
#include <hip/hip_runtime.h>
#include <math.h>

#define N_PER_B   262144
#define BATCH     8
#define NFEAT     14
#define TPB       256
#define BPB       128                     // blocks per batch
#define BLOCKS    (BPB * BATCH)           // 1024 total (4 blocks/CU)
#define TPBATCH   (BPB * TPB)             // 32768 threads per batch
#define RPT       (N_PER_B / TPBATCH)     // 8 records per thread

// dword-aligned (not 16B-aligned) float4: quat lives at byte offset 56r+28.
typedef float f4u __attribute__((ext_vector_type(4), aligned(4)));

// ---- per-quaternion math (fp32, identical to validated rounds 1-7) ----
__device__ inline void quat_accum(float w, float x, float y, float z, double* s) {
    w = fminf(fmaxf(w, -1000.0f), 1000.0f);
    x = fminf(fmaxf(x, -1000.0f), 1000.0f);
    y = fminf(fmaxf(y, -1000.0f), 1000.0f);
    z = fminf(fmaxf(z, -1000.0f), 1000.0f);
    float nrm = sqrtf(w * w + x * x + y * y + z * z);
    nrm = fmaxf(nrm, 1e-8f);
    float inv = 1.0f / nrm;
    w *= inv; x *= inv; y *= inv; z *= inv;
    float r0 = 2.0f * (x * z + w * y);
    float r1 = 2.0f * (y * z - w * x);
    float r2 = 1.0f - 2.0f * (x * x + y * y);
    s[0] += (double)r0 * (double)r0;
    s[1] += (double)r1 * (double)r1;
    s[2] += (double)r2 * (double)r2;
    s[3] += (double)r0 * (double)r1;
    s[4] += (double)r0 * (double)r2;
    s[5] += (double)r1 * (double)r2;
}

// ---- kernel A: streaming accumulate -> partials[block][6] ----
__global__ __launch_bounds__(TPB) void accum_kernel(const float* __restrict__ g,
                                                    double* __restrict__ partials) {
    const int b     = blockIdx.y;
    const int tid_b = blockIdx.x * TPB + threadIdx.x;
    const float* __restrict__ gb = g + (size_t)b * N_PER_B * NFEAT;

    double s[6] = {0, 0, 0, 0, 0, 0};

    // 8 independent unaligned 16B NONTEMPORAL loads per thread (deep MLP;
    // zero-reuse stream bypasses L2 allocation via nt).
    #pragma unroll
    for (int k = 0; k < RPT; ++k) {
        const size_t rec = (size_t)(tid_b + k * TPBATCH);
        f4u q = __builtin_nontemporal_load((const f4u*)(gb + rec * NFEAT + 7));
        quat_accum(q[0], q[1], q[2], q[3], s);
    }

    // 64-lane wave reduction
    #pragma unroll
    for (int off = 32; off > 0; off >>= 1) {
        #pragma unroll
        for (int k = 0; k < 6; ++k) s[k] += __shfl_down(s[k], off);
    }

    __shared__ double lds[TPB / 64][6];
    const int wave = threadIdx.x >> 6;
    const int lane = threadIdx.x & 63;
    if (lane == 0) {
        #pragma unroll
        for (int k = 0; k < 6; ++k) lds[wave][k] = s[k];
    }
    __syncthreads();
    if (threadIdx.x == 0) {
        double* p = partials + (size_t)(b * BPB + blockIdx.x) * 6;
        #pragma unroll
        for (int k = 0; k < 6; ++k)
            p[k] = lds[0][k] + lds[1][k] + lds[2][k] + lds[3][k];
    }
}

// ---- closed-form 3x3 symmetric eigenvalues -> per-batch loss (fp64) ----
__device__ inline double batch_loss(const double* sraw) {
    const double invN = 1.0 / (double)N_PER_B;
    double a00 = sraw[0] * invN, a11 = sraw[1] * invN, a22 = sraw[2] * invN;
    double a01 = sraw[3] * invN, a02 = sraw[4] * invN, a12 = sraw[5] * invN;

    a00 = fmin(fmax(a00, -1e6), 1e6);
    a11 = fmin(fmax(a11, -1e6), 1e6);
    a22 = fmin(fmax(a22, -1e6), 1e6);
    a01 = fmin(fmax(a01, -1e6), 1e6);
    a02 = fmin(fmax(a02, -1e6), 1e6);
    a12 = fmin(fmax(a12, -1e6), 1e6);

    double q  = (a00 + a11 + a22) / 3.0;
    double p1 = a01 * a01 + a02 * a02 + a12 * a12;
    double d0 = a00 - q, d1 = a11 - q, d2 = a22 - q;
    double p2 = d0 * d0 + d1 * d1 + d2 * d2 + 2.0 * p1;

    double eigmax, eigmin;
    if (p2 <= 0.0) {
        eigmax = q;
        eigmin = q;
    } else {
        double p = sqrt(p2 / 6.0);
        double invp = 1.0 / p;
        double b00 = d0 * invp, b11 = d1 * invp, b22 = d2 * invp;
        double b01 = a01 * invp, b02 = a02 * invp, b12 = a12 * invp;
        double detB = b00 * (b11 * b22 - b12 * b12)
                    - b01 * (b01 * b22 - b12 * b02)
                    + b02 * (b01 * b12 - b11 * b02);
        double r = 0.5 * detB;
        r = fmin(1.0, fmax(-1.0, r));
        double phi = acos(r) / 3.0;
        eigmax = q + 2.0 * p * cos(phi);
        eigmin = q + 2.0 * p * cos(phi + 2.0 * M_PI / 3.0);
    }

    double max_safe = fmax(eigmax, 1e-6);
    double min_safe = fmax(eigmin, 1e-6);
    double ratio = max_safe / min_safe;
    ratio = fmin(fmax(ratio, 1.0), 1e6);
    return -log(ratio);
}

// ---- kernel B: reduce 1024x6 partials + eigen + mean (one block) ----
__global__ void finalize_kernel(const double* __restrict__ partials,
                                float* __restrict__ out) {
    // 32 lanes per batch (8 batches x 32 = 256 threads); each lane sums 4
    const int bb = threadIdx.x >> 5;
    const int l  = threadIdx.x & 31;
    double t[6] = {0, 0, 0, 0, 0, 0};
    #pragma unroll
    for (int j = 0; j < BPB / 32; ++j) {
        const double* pp = partials + (size_t)(bb * BPB + l + 32 * j) * 6;
        #pragma unroll
        for (int k = 0; k < 6; ++k) t[k] += pp[k];
    }
    #pragma unroll
    for (int off = 16; off > 0; off >>= 1) {
        #pragma unroll
        for (int k = 0; k < 6; ++k) t[k] += __shfl_down(t[k], off, 32);
    }

    __shared__ double Tsum[BATCH][6];
    if (l == 0) {
        #pragma unroll
        for (int k = 0; k < 6; ++k) Tsum[bb][k] = t[k];
    }
    __syncthreads();

    __shared__ double losses[BATCH];
    if (threadIdx.x < BATCH) losses[threadIdx.x] = batch_loss(Tsum[threadIdx.x]);
    __syncthreads();

    if (threadIdx.x == 0) {
        double ssum = 0.0;
        #pragma unroll
        for (int i = 0; i < BATCH; ++i) ssum += losses[i];
        out[0] = (float)(ssum / (double)BATCH);
    }
}

extern "C" void kernel_launch(void* const* d_in, const int* in_sizes, int n_in,
                              void* d_out, int out_size, void* d_ws, size_t ws_size,
                              hipStream_t stream) {
    const float* g = (const float*)d_in[0];
    float* out = (float*)d_out;
    double* partials = (double*)d_ws;  // BLOCKS*6 doubles = 48 KB, fully
                                       // overwritten every call (poison-safe)

    accum_kernel<<<dim3(BPB, BATCH), TPB, 0, stream>>>(g, partials);
    finalize_kernel<<<1, TPB, 0, stream>>>(partials, out);
}

// Round 9
// 24.506 us; speedup vs baseline: 5.0767x; 1.0315x over previous
//
#include <hip/hip_runtime.h>
#include <math.h>

#define N_PER_B   262144
#define BATCH     8
#define NFEAT     14
#define TPB       256
#define BPB       64                      // blocks per batch
#define BLOCKS    (BPB * BATCH)           // 512 total (2 blocks/CU)
#define TPBATCH   (BPB * TPB)             // 16384 threads per batch
#define RPT       (N_PER_B / TPBATCH)     // 16 records per thread

// dword-aligned (not 16B-aligned) float4: quat lives at byte offset 56r+28.
typedef float f4u __attribute__((ext_vector_type(4), aligned(4)));

// ---- per-quaternion math (fp32, identical to validated rounds 1-8) ----
__device__ inline void quat_accum(float w, float x, float y, float z, double* s) {
    w = fminf(fmaxf(w, -1000.0f), 1000.0f);
    x = fminf(fmaxf(x, -1000.0f), 1000.0f);
    y = fminf(fmaxf(y, -1000.0f), 1000.0f);
    z = fminf(fmaxf(z, -1000.0f), 1000.0f);
    float nrm = sqrtf(w * w + x * x + y * y + z * z);
    nrm = fmaxf(nrm, 1e-8f);
    float inv = 1.0f / nrm;
    w *= inv; x *= inv; y *= inv; z *= inv;
    float r0 = 2.0f * (x * z + w * y);
    float r1 = 2.0f * (y * z - w * x);
    float r2 = 1.0f - 2.0f * (x * x + y * y);
    s[0] += (double)r0 * (double)r0;
    s[1] += (double)r1 * (double)r1;
    s[2] += (double)r2 * (double)r2;
    s[3] += (double)r0 * (double)r1;
    s[4] += (double)r0 * (double)r2;
    s[5] += (double)r1 * (double)r2;
}

// ---- kernel A: streaming accumulate -> partials[block][6] ----
__global__ __launch_bounds__(TPB) void accum_kernel(const float* __restrict__ g,
                                                    double* __restrict__ partials) {
    const int b     = blockIdx.y;
    const int tid_b = blockIdx.x * TPB + threadIdx.x;
    const float* __restrict__ gb = g + (size_t)b * N_PER_B * NFEAT;

    double s[6] = {0, 0, 0, 0, 0, 0};

    // 16 independent unaligned 16B NONTEMPORAL loads per thread (deep MLP;
    // zero-reuse stream bypasses L2 allocation via nt).
    #pragma unroll
    for (int k = 0; k < RPT; ++k) {
        const size_t rec = (size_t)(tid_b + k * TPBATCH);
        f4u q = __builtin_nontemporal_load((const f4u*)(gb + rec * NFEAT + 7));
        quat_accum(q[0], q[1], q[2], q[3], s);
    }

    // 64-lane wave reduction
    #pragma unroll
    for (int off = 32; off > 0; off >>= 1) {
        #pragma unroll
        for (int k = 0; k < 6; ++k) s[k] += __shfl_down(s[k], off);
    }

    __shared__ double lds[TPB / 64][6];
    const int wave = threadIdx.x >> 6;
    const int lane = threadIdx.x & 63;
    if (lane == 0) {
        #pragma unroll
        for (int k = 0; k < 6; ++k) lds[wave][k] = s[k];
    }
    __syncthreads();
    if (threadIdx.x == 0) {
        double* p = partials + (size_t)(b * BPB + blockIdx.x) * 6;
        #pragma unroll
        for (int k = 0; k < 6; ++k)
            p[k] = lds[0][k] + lds[1][k] + lds[2][k] + lds[3][k];
    }
}

// ---- closed-form 3x3 symmetric eigenvalues -> per-batch loss (fp64) ----
__device__ inline double batch_loss(const double* sraw) {
    const double invN = 1.0 / (double)N_PER_B;
    double a00 = sraw[0] * invN, a11 = sraw[1] * invN, a22 = sraw[2] * invN;
    double a01 = sraw[3] * invN, a02 = sraw[4] * invN, a12 = sraw[5] * invN;

    a00 = fmin(fmax(a00, -1e6), 1e6);
    a11 = fmin(fmax(a11, -1e6), 1e6);
    a22 = fmin(fmax(a22, -1e6), 1e6);
    a01 = fmin(fmax(a01, -1e6), 1e6);
    a02 = fmin(fmax(a02, -1e6), 1e6);
    a12 = fmin(fmax(a12, -1e6), 1e6);

    double q  = (a00 + a11 + a22) / 3.0;
    double p1 = a01 * a01 + a02 * a02 + a12 * a12;
    double d0 = a00 - q, d1 = a11 - q, d2 = a22 - q;
    double p2 = d0 * d0 + d1 * d1 + d2 * d2 + 2.0 * p1;

    double eigmax, eigmin;
    if (p2 <= 0.0) {
        eigmax = q;
        eigmin = q;
    } else {
        double p = sqrt(p2 / 6.0);
        double invp = 1.0 / p;
        double b00 = d0 * invp, b11 = d1 * invp, b22 = d2 * invp;
        double b01 = a01 * invp, b02 = a02 * invp, b12 = a12 * invp;
        double detB = b00 * (b11 * b22 - b12 * b12)
                    - b01 * (b01 * b22 - b12 * b02)
                    + b02 * (b01 * b12 - b11 * b02);
        double r = 0.5 * detB;
        r = fmin(1.0, fmax(-1.0, r));
        double phi = acos(r) / 3.0;
        eigmax = q + 2.0 * p * cos(phi);
        eigmin = q + 2.0 * p * cos(phi + 2.0 * M_PI / 3.0);
    }

    double max_safe = fmax(eigmax, 1e-6);
    double min_safe = fmax(eigmin, 1e-6);
    double ratio = max_safe / min_safe;
    ratio = fmin(fmax(ratio, 1.0), 1e6);
    return -log(ratio);
}

// ---- kernel B: reduce 512x6 partials + eigen + mean (one block) ----
__global__ void finalize_kernel(const double* __restrict__ partials,
                                float* __restrict__ out) {
    // 32 lanes per batch (8 batches x 32 = 256 threads); each lane sums 2
    const int bb = threadIdx.x >> 5;
    const int l  = threadIdx.x & 31;
    double t[6] = {0, 0, 0, 0, 0, 0};
    #pragma unroll
    for (int j = 0; j < BPB / 32; ++j) {
        const double* pp = partials + (size_t)(bb * BPB + l + 32 * j) * 6;
        #pragma unroll
        for (int k = 0; k < 6; ++k) t[k] += pp[k];
    }
    #pragma unroll
    for (int off = 16; off > 0; off >>= 1) {
        #pragma unroll
        for (int k = 0; k < 6; ++k) t[k] += __shfl_down(t[k], off, 32);
    }

    __shared__ double Tsum[BATCH][6];
    if (l == 0) {
        #pragma unroll
        for (int k = 0; k < 6; ++k) Tsum[bb][k] = t[k];
    }
    __syncthreads();

    __shared__ double losses[BATCH];
    if (threadIdx.x < BATCH) losses[threadIdx.x] = batch_loss(Tsum[threadIdx.x]);
    __syncthreads();

    if (threadIdx.x == 0) {
        double ssum = 0.0;
        #pragma unroll
        for (int i = 0; i < BATCH; ++i) ssum += losses[i];
        out[0] = (float)(ssum / (double)BATCH);
    }
}

extern "C" void kernel_launch(void* const* d_in, const int* in_sizes, int n_in,
                              void* d_out, int out_size, void* d_ws, size_t ws_size,
                              hipStream_t stream) {
    const float* g = (const float*)d_in[0];
    float* out = (float*)d_out;
    double* partials = (double*)d_ws;  // BLOCKS*6 doubles = 24 KB, fully
                                       // overwritten every call (poison-safe)

    accum_kernel<<<dim3(BPB, BATCH), TPB, 0, stream>>>(g, partials);
    finalize_kernel<<<1, TPB, 0, stream>>>(partials, out);
}